// Round 5
// baseline (723.582 us; speedup 1.0000x reference)
//
#include <hip/hip_runtime.h>
#include <stdint.h>

#define NNODES 50000
#define NROWS_PAD 50048            // 391 * 128
#define NEDGES 1000000
#define FD 256
#define NCPAD 384                  // padded content/proj1 K dim (3*128)
#define EDIM 64
#define NSCAN ((NNODES + 255) / 256)   // 196 scan blocks

typedef unsigned short u16;
typedef __attribute__((ext_vector_type(8))) short short8;   // 8 x bf16 bits (MFMA A/B frag)
typedef __attribute__((ext_vector_type(4))) float floatx4;

__device__ __forceinline__ float bf2f(u16 x) {
    union { unsigned u; float f; } c; c.u = ((unsigned)x) << 16; return c.f;
}
__device__ __forceinline__ u16 f2bf(float f) {
    union { float f; unsigned u; } c; c.f = f;
    unsigned u = c.u;
    return (u16)((u + 0x7fffu + ((u >> 16) & 1u)) >> 16);   // round-to-nearest-even
}
// async global->LDS, 16B per lane; LDS dest = wave-uniform base + lane*16 (m97 pattern)
__device__ __forceinline__ void gload16(const u16* g, u16* l) {
    __builtin_amdgcn_global_load_lds(
        (const __attribute__((address_space(1))) void*)g,
        (__attribute__((address_space(3))) void*)l, 16, 0, 0);
}

// ---------- runtime input-dtype probe (f32 vs bf16 harness feed) ----------
__global__ void detect_kernel(const u16* p, int* flag) {
    __shared__ int smax;
    if (threadIdx.x == 0) smax = 0;
    __syncthreads();
    int m = 0;
    for (int i = threadIdx.x; i < 8192; i += 256) {
        int e = (p[i] >> 7) & 0xFF;
        m = m > e ? m : e;
    }
    atomicMax(&smax, m);
    __syncthreads();
    if (threadIdx.x == 0) *flag = (smax >= 140) ? 1 : 0;
}

// ---------- prep: weight convert + int4-vectorized edge count -----------------
#define NB_CONV 1798               // ceil(920192/512)
#define NB_CNT4 489                // ceil(1e6/(512*4))
#define PREP_GRID (NB_CONV + NB_CNT4)
__global__ __launch_bounds__(512) void prep_kernel(
    u16* arena, const int* flagp,
    const void* wexp, const void* bexp, const void* wp1, const void* bp1,
    const void* wp2, const void* bp2, const void* wconv, const void* bconv,
    const void* wo1, const void* bo1, const void* wo2, const void* bo2,
    const int* dst, int* deg)
{
    const int bid = blockIdx.x;
    if (bid >= NB_CONV) {                // ---- edge count role (4 edges/thread) ----
        int base = ((bid - NB_CONV) * 512 + threadIdx.x) * 4;
        if (base < NEDGES) {             // base%4==0 -> base+3 < NEDGES too
            int4 d = *(const int4*)(dst + base);
            atomicAdd(&deg[d.x], 1);
            atomicAdd(&deg[d.y], 1);
            atomicAdd(&deg[d.z], 1);
            atomicAdd(&deg[d.w], 1);
        }
        return;
    }
    // ---- weights -> padded bf16 arena ----
    const int offs[13]  = {0,16384,16640,164096,164480,262784,263040,
                           656256,657024,788096,788608,919680,920192};
    const int rreal[12] = {256,1,300,1,256,1,768,1,512,1,512,1};
    const int creal[12] = {64,256,300,300,300,256,512,768,256,512,256,512};
    const int cpd[12]   = {64,256,384,384,384,256,512,768,256,512,256,512};
    long gid = (long)bid * 512 + threadIdx.x;
    if (gid >= 920192) return;
    const void* srcs[12] = {wexp,bexp,wp1,bp1,wp2,bp2,wconv,bconv,wo1,bo1,wo2,bo2};
    int fl = *flagp;
    int t = 0;
    #pragma unroll
    for (int i = 1; i < 12; ++i) if (gid >= offs[i]) t = i;
    long local = gid - offs[t];
    int rr = (int)(local / cpd[t]);
    int cc = (int)(local % cpd[t]);
    u16 v = 0;
    if (rr < rreal[t] && cc < creal[t]) {
        long si = (long)rr * creal[t] + cc;
        v = fl ? f2bf(((const float*)srcs[t])[si]) : ((const u16*)srcs[t])[si];
    }
    arena[gid] = v;
}

// ---------------- CSR scans ----------------
__global__ __launch_bounds__(256) void scan1_kernel(const int* deg, int* bsum) {
    __shared__ int s[256];
    int t = threadIdx.x;
    int i = blockIdx.x * 256 + t;
    s[t] = (i < NNODES) ? deg[i] : 0;
    __syncthreads();
    #pragma unroll
    for (int off = 128; off > 0; off >>= 1) {
        if (t < off) s[t] += s[t + off];
        __syncthreads();
    }
    if (t == 0) bsum[blockIdx.x] = s[0];
}

__global__ __launch_bounds__(256) void scan2_kernel(int* bsum, int* row_start) {
    __shared__ int s[256];
    int t = threadIdx.x;
    int v = (t < NSCAN) ? bsum[t] : 0;
    s[t] = v;
    __syncthreads();
    for (int off = 1; off < 256; off <<= 1) {
        int x = (t >= off) ? s[t - off] : 0;
        __syncthreads();
        s[t] += x;
        __syncthreads();
    }
    if (t < NSCAN) bsum[t] = s[t] - v;   // exclusive
    if (t == 0) row_start[NNODES] = NEDGES;
}

__global__ __launch_bounds__(256) void scan3_kernel(const int* deg, const int* bsum,
        int* row_start, int* cursor, float* inv_w) {
    __shared__ int s[256];
    int t = threadIdx.x;
    int i = blockIdx.x * 256 + t;
    int v = (i < NNODES) ? deg[i] : 0;
    s[t] = v;
    __syncthreads();
    for (int off = 1; off < 256; off <<= 1) {
        int x = (t >= off) ? s[t - off] : 0;
        __syncthreads();
        s[t] += x;
        __syncthreads();
    }
    if (i < NNODES) {
        int base = bsum[blockIdx.x] + s[t] - v;
        row_start[i] = base;
        cursor[i] = base;
        inv_w[i] = 1.0f / (float)(v > 0 ? v : 1);
    }
}

// -------- union: fused init (proj1->proj2->expansion) + CSR fill --------------
// Block roles (per 13): r<8 -> init block (MFMA-heavy), r>=8 -> fill chunk
// (4 edges/thread int4, atomic/scatter-heavy; ILP x4 vs round-4).
#define IF_GRID (98 * 13)          // 1274: 782 init (+2 skip) + 489 fill (+1 skip)
__global__ __launch_bounds__(512, 4) void initfill_kernel(
    const void* __restrict__ content, const void* __restrict__ emb,
    const int* __restrict__ flagp,
    const u16* __restrict__ Wp1, const u16* __restrict__ bp1,
    const u16* __restrict__ Wp2, const u16* __restrict__ bp2,
    const u16* __restrict__ Wexp, const u16* __restrict__ bexp,
    u16* __restrict__ hbuf,
    const int* __restrict__ src, const int* __restrict__ dst,
    int* __restrict__ cursor, int* __restrict__ esrc)
{
    __shared__ __align__(16) u16 sA[64 * 64];    //  8 KB  (emb A-tile, swizzled)
    __shared__ __align__(16) u16 sB[384 * 32];   // 24 KB  (B k-plane)
    __shared__ __align__(16) u16 T[64 * 384];    // 48 KB  (content A-tile, then C1)

    const int g13 = blockIdx.x / 13, r13 = blockIdx.x % 13;
    if (r13 >= 8) {                      // ---- fill role (4 edges/thread) ----
        int fb = g13 * 5 + (r13 - 8);
        if (fb >= NB_CNT4) return;
        int base = (fb * 512 + threadIdx.x) * 4;
        if (base < NEDGES) {
            int4 s4 = *(const int4*)(src + base);
            int4 d4 = *(const int4*)(dst + base);
            int p0 = atomicAdd(&cursor[d4.x], 1);
            int p1 = atomicAdd(&cursor[d4.y], 1);
            int p2 = atomicAdd(&cursor[d4.z], 1);
            int p3 = atomicAdd(&cursor[d4.w], 1);
            if ((unsigned)p0 < (unsigned)NEDGES) esrc[p0] = s4.x;
            if ((unsigned)p1 < (unsigned)NEDGES) esrc[p1] = s4.y;
            if ((unsigned)p2 < (unsigned)NEDGES) esrc[p2] = s4.z;
            if ((unsigned)p3 < (unsigned)NEDGES) esrc[p3] = s4.w;
        }
        return;
    }
    // ---- init role ----
    const int iid = g13 * 8 + r13;
    if (iid >= 782) return;
    const int bm = iid * 64;
    const int t = threadIdx.x;
    const int wave = t >> 6, lane = t & 63;
    const int quad = lane >> 4, l16 = lane & 15;
    const int wm = wave >> 2, wn = wave & 3;     // wave tile: 32 rows (x N cols)
    const int lrow = lane >> 2, lcol = (lane & 3) * 8;
    const int fl = *flagp;

    // ---- stage emb A-tile (64x64) -> sA, converted, XOR-swizzled -------------
    {
        int row = t >> 3;                // 0..63
        int c0 = (t & 7) * 8;            // 0..56
        int gm = bm + row;
        u16 o[8];
        if (gm < NNODES) {
            if (fl) {
                const float* ep = (const float*)emb + (size_t)gm * EDIM + c0;
                float4 x = *(const float4*)ep;
                float4 y = *(const float4*)(ep + 4);
                o[0]=f2bf(x.x); o[1]=f2bf(x.y); o[2]=f2bf(x.z); o[3]=f2bf(x.w);
                o[4]=f2bf(y.x); o[5]=f2bf(y.y); o[6]=f2bf(y.z); o[7]=f2bf(y.w);
            } else {
                const u16* ep = (const u16*)emb + (size_t)gm * EDIM + c0;
                ushort4 x = *(const ushort4*)ep;
                ushort4 y = *(const ushort4*)(ep + 4);
                o[0]=x.x; o[1]=x.y; o[2]=x.z; o[3]=x.w;
                o[4]=y.x; o[5]=y.y; o[6]=y.z; o[7]=y.w;
            }
        } else {
            #pragma unroll
            for (int k = 0; k < 8; ++k) o[k] = 0;
        }
        // 16B-aligned after XOR (index multiple of 8 u16; XOR flips bits 3..5)
        u16* d = &sA[(row * 64 + c0) ^ ((row & 7) << 3)];
        *(ushort4*)d = (ushort4){o[0], o[1], o[2], o[3]};
        *(ushort4*)(d + 4) = (ushort4){o[4], o[5], o[6], o[7]};
    }
    // ---- stage content A-tile (64x384, 300 real cols) -> T, converted --------
    #pragma unroll
    for (int j = 0; j < 6; ++j) {
        int idx = (j * 512 + t) * 8;     // 0..24568
        int row = idx / 384;
        int c0 = idx % 384;              // multiple of 8
        int gm = bm + row;
        u16 o[8];
        if (gm < NNODES && c0 + 8 <= 300) {
            if (fl) {
                const float* cp = (const float*)content + (size_t)gm * 300 + c0;
                float4 x = *(const float4*)cp;
                float4 y = *(const float4*)(cp + 4);
                o[0]=f2bf(x.x); o[1]=f2bf(x.y); o[2]=f2bf(x.z); o[3]=f2bf(x.w);
                o[4]=f2bf(y.x); o[5]=f2bf(y.y); o[6]=f2bf(y.z); o[7]=f2bf(y.w);
            } else {
                const u16* cp = (const u16*)content + (size_t)gm * 300 + c0;
                ushort4 x = *(const ushort4*)cp;       // 8B-aligned (row*600%8==0)
                ushort4 y = *(const ushort4*)(cp + 4);
                o[0]=x.x; o[1]=x.y; o[2]=x.z; o[3]=x.w;
                o[4]=y.x; o[5]=y.y; o[6]=y.z; o[7]=y.w;
            }
        } else if (gm < NNODES && c0 < 300) {          // partial chunk (c0==296)
            #pragma unroll
            for (int k = 0; k < 8; ++k) {
                int c = c0 + k;
                o[k] = (c < 300)
                    ? (fl ? f2bf(((const float*)content)[(size_t)gm * 300 + c])
                          : ((const u16*)content)[(size_t)gm * 300 + c])
                    : (u16)0;
            }
        } else {
            #pragma unroll
            for (int k = 0; k < 8; ++k) o[k] = 0;
        }
        u16* d = &T[(row * 384 + c0) ^ ((row & 7) << 3)];
        *(ushort4*)d = (ushort4){o[0], o[1], o[2], o[3]};
        *(ushort4*)(d + 4) = (ushort4){o[4], o[5], o[6], o[7]};
    }
    __syncthreads();

    // ---------------- phase 1: proj1, K=384, N=384, A = T ---------------------
    floatx4 a1[2][6];
    #pragma unroll
    for (int i = 0; i < 2; ++i)
        #pragma unroll
        for (int j = 0; j < 6; ++j) a1[i][j] = (floatx4){0.f, 0.f, 0.f, 0.f};
    for (int kt = 0; kt < 384; kt += 32) {
        #pragma unroll
        for (int c = 0; c < 3; ++c) {
            int r0 = wave * 48 + c * 16;
            gload16(Wp1 + (size_t)(r0 + lrow) * NCPAD + kt + lcol, &sB[r0 * 32]);
        }
        __syncthreads();
        short8 af[2];
        #pragma unroll
        for (int mt = 0; mt < 2; ++mt) {
            int row = wm * 32 + mt * 16 + l16;
            af[mt] = *(const short8*)&T[(row * 384 + kt + quad * 8) ^ ((row & 7) << 3)];
        }
        #pragma unroll
        for (int nt = 0; nt < 6; ++nt) {
            short8 bf = *(const short8*)&sB[(wn * 96 + nt * 16 + l16) * 32 + quad * 8];
            a1[0][nt] = __builtin_amdgcn_mfma_f32_16x16x32_bf16(af[0], bf, a1[0][nt], 0, 0, 0);
            a1[1][nt] = __builtin_amdgcn_mfma_f32_16x16x32_bf16(af[1], bf, a1[1][nt], 0, 0, 0);
        }
        __syncthreads();
    }
    // epilogue 1: bias + lrelu -> overwrite T (all A reads done at last barrier)
    #pragma unroll
    for (int nt = 0; nt < 6; ++nt) {
        int col = wn * 96 + nt * 16 + l16;
        float bv = bf2f(bp1[col]);
        #pragma unroll
        for (int mt = 0; mt < 2; ++mt)
            #pragma unroll
            for (int rr = 0; rr < 4; ++rr) {
                int row = wm * 32 + mt * 16 + quad * 4 + rr;
                float v = a1[mt][nt][rr] + bv;
                v = v > 0.f ? v : 0.1f * v;
                T[(row * NCPAD + col) ^ ((row & 7) << 3)] = f2bf(v);
            }
    }
    __syncthreads();

    // ---------------- phase 2: proj2, K=384, A = T (LDS), N=256 ---------------
    floatx4 a2[2][4];
    #pragma unroll
    for (int i = 0; i < 2; ++i)
        #pragma unroll
        for (int j = 0; j < 4; ++j) a2[i][j] = (floatx4){0.f, 0.f, 0.f, 0.f};
    for (int kt = 0; kt < 384; kt += 32) {
        #pragma unroll
        for (int c = 0; c < 2; ++c) {
            int r0 = wave * 32 + c * 16;
            gload16(Wp2 + (size_t)(r0 + lrow) * NCPAD + kt + lcol, &sB[r0 * 32]);
        }
        __syncthreads();
        short8 af[2];
        #pragma unroll
        for (int mt = 0; mt < 2; ++mt) {
            int row = wm * 32 + mt * 16 + l16;
            af[mt] = *(const short8*)&T[(row * NCPAD + kt + quad * 8) ^ ((row & 7) << 3)];
        }
        #pragma unroll
        for (int nt = 0; nt < 4; ++nt) {
            short8 bf = *(const short8*)&sB[(wn * 64 + nt * 16 + l16) * 32 + quad * 8];
            a2[0][nt] = __builtin_amdgcn_mfma_f32_16x16x32_bf16(af[0], bf, a2[0][nt], 0, 0, 0);
            a2[1][nt] = __builtin_amdgcn_mfma_f32_16x16x32_bf16(af[1], bf, a2[1][nt], 0, 0, 0);
        }
        __syncthreads();
    }

    // ---------------- phase 3: expansion, K=64, N=256, A = sA -----------------
    floatx4 aE[2][4];
    #pragma unroll
    for (int i = 0; i < 2; ++i)
        #pragma unroll
        for (int j = 0; j < 4; ++j) aE[i][j] = (floatx4){0.f, 0.f, 0.f, 0.f};
    for (int kt = 0; kt < 64; kt += 32) {
        #pragma unroll
        for (int c = 0; c < 2; ++c) {
            int r0 = wave * 32 + c * 16;
            gload16(Wexp + (size_t)(r0 + lrow) * EDIM + kt + lcol, &sB[r0 * 32]);
        }
        __syncthreads();
        short8 af[2];
        #pragma unroll
        for (int mt = 0; mt < 2; ++mt) {
            int row = wm * 32 + mt * 16 + l16;
            af[mt] = *(const short8*)&sA[(row * 64 + kt + quad * 8) ^ ((row & 7) << 3)];
        }
        #pragma unroll
        for (int nt = 0; nt < 4; ++nt) {
            short8 bf = *(const short8*)&sB[(wn * 64 + nt * 16 + l16) * 32 + quad * 8];
            aE[0][nt] = __builtin_amdgcn_mfma_f32_16x16x32_bf16(af[0], bf, aE[0][nt], 0, 0, 0);
            aE[1][nt] = __builtin_amdgcn_mfma_f32_16x16x32_bf16(af[1], bf, aE[1][nt], 0, 0, 0);
        }
        __syncthreads();
    }

    // epilogue: h = lrelu(E + bexp) + lrelu(C2 + bp2) -> hbuf
    #pragma unroll
    for (int nt = 0; nt < 4; ++nt) {
        int col = wn * 64 + nt * 16 + l16;
        float bE = bf2f(bexp[col]), b2 = bf2f(bp2[col]);
        #pragma unroll
        for (int mt = 0; mt < 2; ++mt)
            #pragma unroll
            for (int rr = 0; rr < 4; ++rr) {
                int row = wm * 32 + mt * 16 + quad * 4 + rr;
                int gm = bm + row;
                if (gm < NNODES) {
                    float hE = aE[mt][nt][rr] + bE; hE = hE > 0.f ? hE : 0.1f * hE;
                    float c2 = a2[mt][nt][rr] + b2; c2 = c2 > 0.f ? c2 : 0.1f * c2;
                    hbuf[(size_t)gm * FD + col] = f2bf(hE + c2);
                }
            }
    }
}

// -------- fused layer: gather-agg + conv + norm + Wo1 + Wo2, per 64 rows ------
//   G  = neighbor-mean of this block's 64 nodes (CSR pull)   -> GT (LDS)
//   X  = lrelu([h rows | G] @ Wc^T + bc)    K=512 (2nd half A from LDS)
//   T  = X / max(||X||,1e-6)               (overwrites GT; G dead after conv)
//   Y  = lrelu(T @ W1^T + b1); Z = Y @ W2^T + b2 -> out rows
// out != h (ping-pong): gather may read ANY h row, so no in-place write.
__global__ __launch_bounds__(512, 4) void flayer_kernel(
    const u16* __restrict__ h, const int* __restrict__ rs,
    const int* __restrict__ esrc, const float* __restrict__ inv_w,
    const u16* __restrict__ Wc, const u16* __restrict__ bc,
    const u16* __restrict__ W1, const u16* __restrict__ b1,
    const u16* __restrict__ W2, const u16* __restrict__ b2,
    u16* __restrict__ out)
{
    __shared__ __align__(16) u16 sA[2][64 * 32];     //  8 KB: A k-tile (h half)
    __shared__ __align__(16) u16 sB[2][256 * 32];    // 32 KB: B k-tile
    __shared__ __align__(16) u16 GT[64 * 256];       // 32 KB: gather tile, then T
    __shared__ float ssq[4][64];                     //  1 KB
    // 73.25 KB -> 2 blocks/CU

    const int t = threadIdx.x;
    const int wave = t >> 6, lane = t & 63;
    const int quad = lane >> 4, l16 = lane & 15;
    const int wm = wave >> 2, wn = wave & 3;         // wave tile: 32 rows x 64 cols
    const int lrow = lane >> 2, lcol = (lane & 3) * 8;
    const int bm = blockIdx.x * 64;

    // ---- step A: gather neighbor-mean for rows [bm, bm+64) -> GT -------------
    #pragma unroll 1
    for (int i = 0; i < 8; ++i) {
        int row = wave * 8 + i;
        int gm = bm + row;
        float a0 = 0.f, a1 = 0.f, a2 = 0.f, a3 = 0.f;
        if (gm < NNODES) {
            int e0 = rs[gm], e1 = rs[gm + 1];
            e0 = max(0, min(e0, NEDGES));
            e1 = max(e0, min(e1, NEDGES));
            int e = e0;
            for (; e + 4 <= e1; e += 4) {
                int u0 = esrc[e + 0]; if ((unsigned)u0 >= (unsigned)NNODES) u0 = 0;
                int u1 = esrc[e + 1]; if ((unsigned)u1 >= (unsigned)NNODES) u1 = 0;
                int u2 = esrc[e + 2]; if ((unsigned)u2 >= (unsigned)NNODES) u2 = 0;
                int u3 = esrc[e + 3]; if ((unsigned)u3 >= (unsigned)NNODES) u3 = 0;
                ushort4 t0 = *(const ushort4*)(h + (size_t)u0 * FD + lane * 4);
                ushort4 t1 = *(const ushort4*)(h + (size_t)u1 * FD + lane * 4);
                ushort4 t2 = *(const ushort4*)(h + (size_t)u2 * FD + lane * 4);
                ushort4 t3 = *(const ushort4*)(h + (size_t)u3 * FD + lane * 4);
                a0 += bf2f(t0.x) + bf2f(t1.x) + bf2f(t2.x) + bf2f(t3.x);
                a1 += bf2f(t0.y) + bf2f(t1.y) + bf2f(t2.y) + bf2f(t3.y);
                a2 += bf2f(t0.z) + bf2f(t1.z) + bf2f(t2.z) + bf2f(t3.z);
                a3 += bf2f(t0.w) + bf2f(t1.w) + bf2f(t2.w) + bf2f(t3.w);
            }
            for (; e < e1; ++e) {
                int u = esrc[e];
                if ((unsigned)u >= (unsigned)NNODES) u = 0;
                ushort4 tv = *(const ushort4*)(h + (size_t)u * FD + lane * 4);
                a0 += bf2f(tv.x); a1 += bf2f(tv.y); a2 += bf2f(tv.z); a3 += bf2f(tv.w);
            }
            float s = inv_w[gm];
            a0 *= s; a1 *= s; a2 *= s; a3 *= s;
        }
        ushort4 ov;
        ov.x = f2bf(a0); ov.y = f2bf(a1); ov.z = f2bf(a2); ov.w = f2bf(a3);
        // 8B chunk stays contiguous under XOR (flips idx bits 3..5 only)
        *(ushort4*)&GT[(row * 256 + lane * 4) ^ ((row & 7) << 3)] = ov;
    }
    __syncthreads();

    floatx4 acc[2][4];
    #pragma unroll
    for (int i = 0; i < 2; ++i)
        #pragma unroll
        for (int j = 0; j < 4; ++j) acc[i][j] = (floatx4){0.f, 0.f, 0.f, 0.f};

    // ---- conv loop 1: k=0..255, A staged from h (global) ---------------------
    for (int kt = 0; kt < 256; kt += 64) {
        {
            int hh = wave & 1, r0 = (wave >> 1) * 16;
            gload16(h + (size_t)(bm + r0 + lrow) * 256 + kt + hh * 32 + lcol,
                    &sA[hh][r0 * 32]);
        }
        #pragma unroll
        for (int c = 0; c < 4; ++c) {
            int hh = c >> 1, r0 = wave * 32 + (c & 1) * 16;
            gload16(Wc + (size_t)(r0 + lrow) * 512 + kt + hh * 32 + lcol,
                    &sB[hh][r0 * 32]);
        }
        __syncthreads();
        #pragma unroll
        for (int g = 0; g < 2; ++g) {
            short8 af[2], bf[4];
            #pragma unroll
            for (int mt = 0; mt < 2; ++mt)
                af[mt] = *(const short8*)&sA[g][(wm * 32 + mt * 16 + l16) * 32 + quad * 8];
            #pragma unroll
            for (int nt = 0; nt < 4; ++nt)
                bf[nt] = *(const short8*)&sB[g][(wn * 64 + nt * 16 + l16) * 32 + quad * 8];
            #pragma unroll
            for (int mt = 0; mt < 2; ++mt)
                #pragma unroll
                for (int nt = 0; nt < 4; ++nt)
                    acc[mt][nt] = __builtin_amdgcn_mfma_f32_16x16x32_bf16(af[mt], bf[nt], acc[mt][nt], 0, 0, 0);
        }
        __syncthreads();
    }
    // ---- conv loop 2: k=256..511, A read directly from GT (LDS) --------------
    for (int kt = 256; kt < 512; kt += 64) {
        #pragma unroll
        for (int c = 0; c < 4; ++c) {
            int hh = c >> 1, r0 = wave * 32 + (c & 1) * 16;
            gload16(Wc + (size_t)(r0 + lrow) * 512 + kt + hh * 32 + lcol,
                    &sB[hh][r0 * 32]);
        }
        __syncthreads();
        #pragma unroll
        for (int g = 0; g < 2; ++g) {
            short8 af[2], bf[4];
            #pragma unroll
            for (int mt = 0; mt < 2; ++mt) {
                int row = wm * 32 + mt * 16 + l16;
                af[mt] = *(const short8*)&GT[(row * 256 + (kt - 256) + g * 32 + quad * 8) ^ ((row & 7) << 3)];
            }
            #pragma unroll
            for (int nt = 0; nt < 4; ++nt)
                bf[nt] = *(const short8*)&sB[g][(wn * 64 + nt * 16 + l16) * 32 + quad * 8];
            #pragma unroll
            for (int mt = 0; mt < 2; ++mt)
                #pragma unroll
                for (int nt = 0; nt < 4; ++nt)
                    acc[mt][nt] = __builtin_amdgcn_mfma_f32_16x16x32_bf16(af[mt], bf[nt], acc[mt][nt], 0, 0, 0);
        }
        __syncthreads();
    }
    // epilogue 1: f32 row-ss -> normalized bf16 -> T (=GT; all G reads done)
    {
        float part[2][4];
        #pragma unroll
        for (int mt = 0; mt < 2; ++mt)
            #pragma unroll
            for (int rr = 0; rr < 4; ++rr) part[mt][rr] = 0.f;
        #pragma unroll
        for (int nt = 0; nt < 4; ++nt) {
            float bv = bf2f(bc[wn * 64 + nt * 16 + l16]);
            #pragma unroll
            for (int mt = 0; mt < 2; ++mt)
                #pragma unroll
                for (int rr = 0; rr < 4; ++rr) {
                    float v = acc[mt][nt][rr] + bv;
                    v = v > 0.f ? v : 0.1f * v;
                    part[mt][rr] += v * v;
                }
        }
        #pragma unroll
        for (int off = 1; off < 16; off <<= 1)
            #pragma unroll
            for (int mt = 0; mt < 2; ++mt)
                #pragma unroll
                for (int rr = 0; rr < 4; ++rr)
                    part[mt][rr] += __shfl_xor(part[mt][rr], off);
        if (l16 == 0)
            #pragma unroll
            for (int mt = 0; mt < 2; ++mt)
                #pragma unroll
                for (int rr = 0; rr < 4; ++rr)
                    ssq[wn][wm * 32 + mt * 16 + quad * 4 + rr] = part[mt][rr];
        __syncthreads();
        #pragma unroll
        for (int mt = 0; mt < 2; ++mt)
            #pragma unroll
            for (int rr = 0; rr < 4; ++rr) {
                int row = wm * 32 + mt * 16 + quad * 4 + rr;
                float s = 1.0f / fmaxf(sqrtf(ssq[0][row] + ssq[1][row] +
                                             ssq[2][row] + ssq[3][row]), 1e-6f);
                #pragma unroll
                for (int nt = 0; nt < 4; ++nt) {
                    int col = wn * 64 + nt * 16 + l16;
                    float v = acc[mt][nt][rr] + bf2f(bc[col]);
                    v = v > 0.f ? v : 0.1f * v;
                    GT[(row * 256 + col) ^ ((row & 7) << 3)] = f2bf(v * s);
                }
            }
        __syncthreads();
    }

    // ---- phase Wo1: K=256, A = GT(LDS) ----
    #pragma unroll
    for (int i = 0; i < 2; ++i)
        #pragma unroll
        for (int j = 0; j < 4; ++j) acc[i][j] = (floatx4){0.f, 0.f, 0.f, 0.f};
    for (int kt = 0; kt < 256; kt += 64) {
        #pragma unroll
        for (int c = 0; c < 4; ++c) {
            int hh = c >> 1, r0 = wave * 32 + (c & 1) * 16;
            gload16(W1 + (size_t)(r0 + lrow) * 256 + kt + hh * 32 + lcol,
                    &sB[hh][r0 * 32]);
        }
        __syncthreads();
        #pragma unroll
        for (int g = 0; g < 2; ++g) {
            short8 af[2], bf[4];
            #pragma unroll
            for (int mt = 0; mt < 2; ++mt) {
                int row = wm * 32 + mt * 16 + l16;
                af[mt] = *(const short8*)&GT[(row * 256 + kt + g * 32 + quad * 8) ^ ((row & 7) << 3)];
            }
            #pragma unroll
            for (int nt = 0; nt < 4; ++nt)
                bf[nt] = *(const short8*)&sB[g][(wn * 64 + nt * 16 + l16) * 32 + quad * 8];
            #pragma unroll
            for (int mt = 0; mt < 2; ++mt)
                #pragma unroll
                for (int nt = 0; nt < 4; ++nt)
                    acc[mt][nt] = __builtin_amdgcn_mfma_f32_16x16x32_bf16(af[mt], bf[nt], acc[mt][nt], 0, 0, 0);
        }
        __syncthreads();
    }
    // epilogue 2: bias + lrelu -> GT
    #pragma unroll
    for (int nt = 0; nt < 4; ++nt) {
        int col = wn * 64 + nt * 16 + l16;
        float bv = bf2f(b1[col]);
        #pragma unroll
        for (int mt = 0; mt < 2; ++mt) {
            #pragma unroll
            for (int r = 0; r < 4; ++r) {
                int row = wm * 32 + mt * 16 + quad * 4 + r;
                float v = acc[mt][nt][r] + bv;
                v = v > 0.f ? v : 0.1f * v;
                GT[(row * 256 + col) ^ ((row & 7) << 3)] = f2bf(v);
            }
        }
    }
    __syncthreads();

    // ---- phase Wo2: K=256, A = GT -> out (bf16) ----
    #pragma unroll
    for (int i = 0; i < 2; ++i)
        #pragma unroll
        for (int j = 0; j < 4; ++j) acc[i][j] = (floatx4){0.f, 0.f, 0.f, 0.f};
    for (int kt = 0; kt < 256; kt += 64) {
        #pragma unroll
        for (int c = 0; c < 4; ++c) {
            int hh = c >> 1, r0 = wave * 32 + (c & 1) * 16;
            gload16(W2 + (size_t)(r0 + lrow) * 256 + kt + hh * 32 + lcol,
                    &sB[hh][r0 * 32]);
        }
        __syncthreads();
        #pragma unroll
        for (int g = 0; g < 2; ++g) {
            short8 af[2], bf[4];
            #pragma unroll
            for (int mt = 0; mt < 2; ++mt) {
                int row = wm * 32 + mt * 16 + l16;
                af[mt] = *(const short8*)&GT[(row * 256 + kt + g * 32 + quad * 8) ^ ((row & 7) << 3)];
            }
            #pragma unroll
            for (int nt = 0; nt < 4; ++nt)
                bf[nt] = *(const short8*)&sB[g][(wn * 64 + nt * 16 + l16) * 32 + quad * 8];
            #pragma unroll
            for (int mt = 0; mt < 2; ++mt)
                #pragma unroll
                for (int nt = 0; nt < 4; ++nt)
                    acc[mt][nt] = __builtin_amdgcn_mfma_f32_16x16x32_bf16(af[mt], bf[nt], acc[mt][nt], 0, 0, 0);
        }
        __syncthreads();
    }
    #pragma unroll
    for (int nt = 0; nt < 4; ++nt) {
        int col = wn * 64 + nt * 16 + l16;
        float bv = bf2f(b2[col]);
        #pragma unroll
        for (int mt = 0; mt < 2; ++mt) {
            #pragma unroll
            for (int r = 0; r < 4; ++r) {
                int row = wm * 32 + mt * 16 + quad * 4 + r;
                int gm = bm + row;
                if (gm < NNODES) {
                    float v = acc[mt][nt][r] + bv;
                    out[(size_t)gm * 256 + col] = f2bf(v);
                }
            }
        }
    }
}

// -------- fused final: gather-agg + conv (K=512) + f32 row L2-norm -> d_out ---
__global__ __launch_bounds__(512, 4) void ffinal_kernel(
    const u16* __restrict__ h, const int* __restrict__ rs,
    const int* __restrict__ esrc, const float* __restrict__ inv_w,
    const u16* __restrict__ Wc, const u16* __restrict__ bc,
    float* __restrict__ out)
{
    __shared__ __align__(16) u16 sA[2][64 * 32];     //  8 KB
    __shared__ __align__(16) u16 sB[2][256 * 32];    // 32 KB
    __shared__ __align__(16) u16 GT[64 * 256];       // 32 KB: gather tile
    __shared__ float ssq[4][64];                     //  1 KB

    const int t = threadIdx.x;
    const int wave = t >> 6, lane = t & 63;
    const int quad = lane >> 4, l16 = lane & 15;
    const int wm = wave >> 2, wn = wave & 3;
    const int lrow = lane >> 2, lcol = (lane & 3) * 8;
    const int bm = blockIdx.x * 64;

    // ---- step A: gather ----
    #pragma unroll 1
    for (int i = 0; i < 8; ++i) {
        int row = wave * 8 + i;
        int gm = bm + row;
        float a0 = 0.f, a1 = 0.f, a2 = 0.f, a3 = 0.f;
        if (gm < NNODES) {
            int e0 = rs[gm], e1 = rs[gm + 1];
            e0 = max(0, min(e0, NEDGES));
            e1 = max(e0, min(e1, NEDGES));
            int e = e0;
            for (; e + 4 <= e1; e += 4) {
                int u0 = esrc[e + 0]; if ((unsigned)u0 >= (unsigned)NNODES) u0 = 0;
                int u1 = esrc[e + 1]; if ((unsigned)u1 >= (unsigned)NNODES) u1 = 0;
                int u2 = esrc[e + 2]; if ((unsigned)u2 >= (unsigned)NNODES) u2 = 0;
                int u3 = esrc[e + 3]; if ((unsigned)u3 >= (unsigned)NNODES) u3 = 0;
                ushort4 t0 = *(const ushort4*)(h + (size_t)u0 * FD + lane * 4);
                ushort4 t1 = *(const ushort4*)(h + (size_t)u1 * FD + lane * 4);
                ushort4 t2 = *(const ushort4*)(h + (size_t)u2 * FD + lane * 4);
                ushort4 t3 = *(const ushort4*)(h + (size_t)u3 * FD + lane * 4);
                a0 += bf2f(t0.x) + bf2f(t1.x) + bf2f(t2.x) + bf2f(t3.x);
                a1 += bf2f(t0.y) + bf2f(t1.y) + bf2f(t2.y) + bf2f(t3.y);
                a2 += bf2f(t0.z) + bf2f(t1.z) + bf2f(t2.z) + bf2f(t3.z);
                a3 += bf2f(t0.w) + bf2f(t1.w) + bf2f(t2.w) + bf2f(t3.w);
            }
            for (; e < e1; ++e) {
                int u = esrc[e];
                if ((unsigned)u >= (unsigned)NNODES) u = 0;
                ushort4 tv = *(const ushort4*)(h + (size_t)u * FD + lane * 4);
                a0 += bf2f(tv.x); a1 += bf2f(tv.y); a2 += bf2f(tv.z); a3 += bf2f(tv.w);
            }
            float s = inv_w[gm];
            a0 *= s; a1 *= s; a2 *= s; a3 *= s;
        }
        ushort4 ov;
        ov.x = f2bf(a0); ov.y = f2bf(a1); ov.z = f2bf(a2); ov.w = f2bf(a3);
        *(ushort4*)&GT[(row * 256 + lane * 4) ^ ((row & 7) << 3)] = ov;
    }
    __syncthreads();

    floatx4 acc[2][4];
    #pragma unroll
    for (int i = 0; i < 2; ++i)
        #pragma unroll
        for (int j = 0; j < 4; ++j) acc[i][j] = (floatx4){0.f, 0.f, 0.f, 0.f};

    for (int kt = 0; kt < 256; kt += 64) {
        {
            int hh = wave & 1, r0 = (wave >> 1) * 16;
            gload16(h + (size_t)(bm + r0 + lrow) * 256 + kt + hh * 32 + lcol,
                    &sA[hh][r0 * 32]);
        }
        #pragma unroll
        for (int c = 0; c < 4; ++c) {
            int hh = c >> 1, r0 = wave * 32 + (c & 1) * 16;
            gload16(Wc + (size_t)(r0 + lrow) * 512 + kt + hh * 32 + lcol,
                    &sB[hh][r0 * 32]);
        }
        __syncthreads();
        #pragma unroll
        for (int g = 0; g < 2; ++g) {
            short8 af[2], bf[4];
            #pragma unroll
            for (int mt = 0; mt < 2; ++mt)
                af[mt] = *(const short8*)&sA[g][(wm * 32 + mt * 16 + l16) * 32 + quad * 8];
            #pragma unroll
            for (int nt = 0; nt < 4; ++nt)
                bf[nt] = *(const short8*)&sB[g][(wn * 64 + nt * 16 + l16) * 32 + quad * 8];
            #pragma unroll
            for (int mt = 0; mt < 2; ++mt)
                #pragma unroll
                for (int nt = 0; nt < 4; ++nt)
                    acc[mt][nt] = __builtin_amdgcn_mfma_f32_16x16x32_bf16(af[mt], bf[nt], acc[mt][nt], 0, 0, 0);
        }
        __syncthreads();
    }
    for (int kt = 256; kt < 512; kt += 64) {
        #pragma unroll
        for (int c = 0; c < 4; ++c) {
            int hh = c >> 1, r0 = wave * 32 + (c & 1) * 16;
            gload16(Wc + (size_t)(r0 + lrow) * 512 + kt + hh * 32 + lcol,
                    &sB[hh][r0 * 32]);
        }
        __syncthreads();
        #pragma unroll
        for (int g = 0; g < 2; ++g) {
            short8 af[2], bf[4];
            #pragma unroll
            for (int mt = 0; mt < 2; ++mt) {
                int row = wm * 32 + mt * 16 + l16;
                af[mt] = *(const short8*)&GT[(row * 256 + (kt - 256) + g * 32 + quad * 8) ^ ((row & 7) << 3)];
            }
            #pragma unroll
            for (int nt = 0; nt < 4; ++nt)
                bf[nt] = *(const short8*)&sB[g][(wn * 64 + nt * 16 + l16) * 32 + quad * 8];
            #pragma unroll
            for (int mt = 0; mt < 2; ++mt)
                #pragma unroll
                for (int nt = 0; nt < 4; ++nt)
                    acc[mt][nt] = __builtin_amdgcn_mfma_f32_16x16x32_bf16(af[mt], bf[nt], acc[mt][nt], 0, 0, 0);
        }
        __syncthreads();
    }
    // epilogue: bias (no act), f32 row-ss, normalized f32 store
    float part[2][4];
    #pragma unroll
    for (int mt = 0; mt < 2; ++mt)
        #pragma unroll
        for (int rr = 0; rr < 4; ++rr) part[mt][rr] = 0.f;
    #pragma unroll
    for (int nt = 0; nt < 4; ++nt) {
        float bv = bf2f(bc[wn * 64 + nt * 16 + l16]);
        #pragma unroll
        for (int mt = 0; mt < 2; ++mt)
            #pragma unroll
            for (int rr = 0; rr < 4; ++rr) {
                float v = acc[mt][nt][rr] + bv;
                part[mt][rr] += v * v;
            }
    }
    #pragma unroll
    for (int off = 1; off < 16; off <<= 1)
        #pragma unroll
        for (int mt = 0; mt < 2; ++mt)
            #pragma unroll
            for (int rr = 0; rr < 4; ++rr)
                part[mt][rr] += __shfl_xor(part[mt][rr], off);
    if (l16 == 0)
        #pragma unroll
        for (int mt = 0; mt < 2; ++mt)
            #pragma unroll
            for (int rr = 0; rr < 4; ++rr)
                ssq[wn][wm * 32 + mt * 16 + quad * 4 + rr] = part[mt][rr];
    __syncthreads();
    #pragma unroll
    for (int mt = 0; mt < 2; ++mt)
        #pragma unroll
        for (int rr = 0; rr < 4; ++rr) {
            int row = wm * 32 + mt * 16 + quad * 4 + rr;
            int gm = bm + row;
            float s = 1.0f / fmaxf(sqrtf(ssq[0][row] + ssq[1][row] +
                                         ssq[2][row] + ssq[3][row]), 1e-6f);
            if (gm < NNODES) {
                #pragma unroll
                for (int nt = 0; nt < 4; ++nt) {
                    int col = wn * 64 + nt * 16 + l16;
                    out[(size_t)gm * 256 + col] = (acc[mt][nt][rr] + bf2f(bc[col])) * s;
                }
            }
        }
}

extern "C" void kernel_launch(void* const* d_in, const int* in_sizes, int n_in,
                              void* d_out, int out_size, void* d_ws, size_t ws_size,
                              hipStream_t stream) {
    const void* content = d_in[1];
    const int* src      = (const int*)d_in[2];
    const int* dst      = (const int*)d_in[3];
    const void* emb     = d_in[4];

    // ---- workspace layout (all offsets 256B-aligned) -------------------------
    char* ws = (char*)d_ws;
    u16* arena = (u16*)(ws);                        // padded weights bf16
    u16* hbufA = (u16*)(ws + 1840640);              // [50048 x 256] bf16
    u16* hbufB = (u16*)(ws + 27465216);             // [50048 x 256] bf16 (ping-pong)
    int*   deg    = (int*)(ws + 78714368);
    int*   rs     = (int*)(ws + 78914560);
    int*   cursor = (int*)(ws + 79114752);
    float* inv_w  = (float*)(ws + 79314944);
    int*   esrc   = (int*)(ws + 79515136);          // 4 MB
    int*   bsum   = (int*)(ws + 83515648);
    int*   flag   = (int*)(ws + 83516672);

    u16* aWexp  = arena;            u16* aBexp  = arena + 16384;
    u16* aWp1   = arena + 16640;    u16* aBp1   = arena + 164096;
    u16* aWp2   = arena + 164480;   u16* aBp2   = arena + 262784;
    u16* aWconv = arena + 263040;   u16* aBconv = arena + 656256;
    u16* aWo1   = arena + 657024;   u16* aBo1   = arena + 788096;
    u16* aWo2   = arena + 788608;   u16* aBo2   = arena + 919680;

    const int MB64 = NROWS_PAD / 64;   // 782

    // ---- dtype probe, then prep (weight convert + vectorized count) ----------
    detect_kernel<<<1, 256, 0, stream>>>((const u16*)content, flag);
    hipMemsetAsync(deg, 0, (size_t)NNODES * 4, stream);
    prep_kernel<<<PREP_GRID, 512, 0, stream>>>(arena, flag,
        d_in[5], d_in[6], d_in[7], d_in[8], d_in[9], d_in[10], d_in[11],
        d_in[12], d_in[13], d_in[14], d_in[15], d_in[16], dst, deg);

    // ---- CSR scans (tiny) ----
    scan1_kernel<<<NSCAN, 256, 0, stream>>>(deg, bsum);
    scan2_kernel<<<1, 256, 0, stream>>>(bsum, rs);
    scan3_kernel<<<NSCAN, 256, 0, stream>>>(deg, bsum, rs, cursor, inv_w);

    // ---- union: fused init (MFMA-heavy, direct src staging) + CSR fill -------
    initfill_kernel<<<IF_GRID, 512, 0, stream>>>(content, emb, flag,
        aWp1, aBp1, aWp2, aBp2, aWexp, aBexp, hbufA, src, dst, cursor, esrc);

    // ---- fused layers (gather + conv + norm + Wo1 + Wo2), ping-pong A<->B ----
    flayer_kernel<<<MB64, 512, 0, stream>>>(hbufA, rs, esrc, inv_w,
        aWconv, aBconv, aWo1, aBo1, aWo2, aBo2, hbufB);
    flayer_kernel<<<MB64, 512, 0, stream>>>(hbufB, rs, esrc, inv_w,
        aWconv + (size_t)1 * FD * 2 * FD, aBconv + FD,
        aWo1 + (size_t)1 * FD * FD, aBo1 + FD,
        aWo2 + (size_t)1 * FD * FD, aBo2 + FD, hbufA);
    ffinal_kernel<<<MB64, 512, 0, stream>>>(hbufA, rs, esrc, inv_w,
        aWconv + (size_t)2 * FD * 2 * FD, aBconv + 2 * FD, (float*)d_out);
}

// Round 6
// 644.778 us; speedup vs baseline: 1.1222x; 1.1222x over previous
//
#include <hip/hip_runtime.h>
#include <stdint.h>

#define NNODES 50000
#define NROWS_PAD 50048            // 391 * 128
#define NEDGES 1000000
#define FD 256
#define NCPAD 384                  // padded content/proj1 K dim (3*128)
#define EDIM 64
#define NSCAN ((NNODES + 255) / 256)   // 196 scan blocks

typedef unsigned short u16;
typedef __attribute__((ext_vector_type(8))) short short8;   // 8 x bf16 bits (MFMA A/B frag)
typedef __attribute__((ext_vector_type(4))) float floatx4;

__device__ __forceinline__ float bf2f(u16 x) {
    union { unsigned u; float f; } c; c.u = ((unsigned)x) << 16; return c.f;
}
__device__ __forceinline__ u16 f2bf(float f) {
    union { float f; unsigned u; } c; c.f = f;
    unsigned u = c.u;
    return (u16)((u + 0x7fffu + ((u >> 16) & 1u)) >> 16);   // round-to-nearest-even
}
// async global->LDS, 16B per lane; LDS dest = wave-uniform base + lane*16 (m97 pattern)
__device__ __forceinline__ void gload16(const u16* g, u16* l) {
    __builtin_amdgcn_global_load_lds(
        (const __attribute__((address_space(1))) void*)g,
        (__attribute__((address_space(3))) void*)l, 16, 0, 0);
}

// ---------- runtime input-dtype probe (f32 vs bf16 harness feed) ----------
__global__ void detect_kernel(const u16* p, int* flag) {
    __shared__ int smax;
    if (threadIdx.x == 0) smax = 0;
    __syncthreads();
    int m = 0;
    for (int i = threadIdx.x; i < 8192; i += 256) {
        int e = (p[i] >> 7) & 0xFF;
        m = m > e ? m : e;
    }
    atomicMax(&smax, m);
    __syncthreads();
    if (threadIdx.x == 0) *flag = (smax >= 140) ? 1 : 0;
}

// ---------- prep: weight convert + int4-vectorized edge count -----------------
#define NB_CONV 1798               // ceil(920192/512)
#define NB_CNT4 489                // ceil(1e6/(512*4))
#define PREP_GRID (NB_CONV + NB_CNT4)
__global__ __launch_bounds__(512) void prep_kernel(
    u16* arena, const int* flagp,
    const void* wexp, const void* bexp, const void* wp1, const void* bp1,
    const void* wp2, const void* bp2, const void* wconv, const void* bconv,
    const void* wo1, const void* bo1, const void* wo2, const void* bo2,
    const int* dst, int* deg)
{
    const int bid = blockIdx.x;
    if (bid >= NB_CONV) {                // ---- edge count role (4 edges/thread) ----
        int base = ((bid - NB_CONV) * 512 + threadIdx.x) * 4;
        if (base < NEDGES) {             // base%4==0 -> base+3 < NEDGES too
            int4 d = *(const int4*)(dst + base);
            atomicAdd(&deg[d.x], 1);
            atomicAdd(&deg[d.y], 1);
            atomicAdd(&deg[d.z], 1);
            atomicAdd(&deg[d.w], 1);
        }
        return;
    }
    // ---- weights -> padded bf16 arena ----
    const int offs[13]  = {0,16384,16640,164096,164480,262784,263040,
                           656256,657024,788096,788608,919680,920192};
    const int rreal[12] = {256,1,300,1,256,1,768,1,512,1,512,1};
    const int creal[12] = {64,256,300,300,300,256,512,768,256,512,256,512};
    const int cpd[12]   = {64,256,384,384,384,256,512,768,256,512,256,512};
    long gid = (long)bid * 512 + threadIdx.x;
    if (gid >= 920192) return;
    const void* srcs[12] = {wexp,bexp,wp1,bp1,wp2,bp2,wconv,bconv,wo1,bo1,wo2,bo2};
    int fl = *flagp;
    int t = 0;
    #pragma unroll
    for (int i = 1; i < 12; ++i) if (gid >= offs[i]) t = i;
    long local = gid - offs[t];
    int rr = (int)(local / cpd[t]);
    int cc = (int)(local % cpd[t]);
    u16 v = 0;
    if (rr < rreal[t] && cc < creal[t]) {
        long si = (long)rr * creal[t] + cc;
        v = fl ? f2bf(((const float*)srcs[t])[si]) : ((const u16*)srcs[t])[si];
    }
    arena[gid] = v;
}

// ---------------- CSR scans ----------------
__global__ __launch_bounds__(256) void scan1_kernel(const int* deg, int* bsum) {
    __shared__ int s[256];
    int t = threadIdx.x;
    int i = blockIdx.x * 256 + t;
    s[t] = (i < NNODES) ? deg[i] : 0;
    __syncthreads();
    #pragma unroll
    for (int off = 128; off > 0; off >>= 1) {
        if (t < off) s[t] += s[t + off];
        __syncthreads();
    }
    if (t == 0) bsum[blockIdx.x] = s[0];
}

__global__ __launch_bounds__(256) void scan2_kernel(int* bsum, int* row_start) {
    __shared__ int s[256];
    int t = threadIdx.x;
    int v = (t < NSCAN) ? bsum[t] : 0;
    s[t] = v;
    __syncthreads();
    for (int off = 1; off < 256; off <<= 1) {
        int x = (t >= off) ? s[t - off] : 0;
        __syncthreads();
        s[t] += x;
        __syncthreads();
    }
    if (t < NSCAN) bsum[t] = s[t] - v;   // exclusive
    if (t == 0) row_start[NNODES] = NEDGES;
}

__global__ __launch_bounds__(256) void scan3_kernel(const int* deg, const int* bsum,
        int* row_start, int* cursor, float* inv_w) {
    __shared__ int s[256];
    int t = threadIdx.x;
    int i = blockIdx.x * 256 + t;
    int v = (i < NNODES) ? deg[i] : 0;
    s[t] = v;
    __syncthreads();
    for (int off = 1; off < 256; off <<= 1) {
        int x = (t >= off) ? s[t - off] : 0;
        __syncthreads();
        s[t] += x;
        __syncthreads();
    }
    if (i < NNODES) {
        int base = bsum[blockIdx.x] + s[t] - v;
        row_start[i] = base;
        cursor[i] = base;
        inv_w[i] = 1.0f / (float)(v > 0 ? v : 1);
    }
}

// -------- union: fused init (proj1->proj2->expansion) + CSR fill --------------
// Block roles (per 13): r<8 -> init block (MFMA-heavy), r>=8 -> fill chunk
// (4 edges/thread int4, atomic/scatter-heavy).
#define IF_GRID (98 * 13)          // 1274: 782 init (+2 skip) + 489 fill (+1 skip)
__global__ __launch_bounds__(512, 4) void initfill_kernel(
    const void* __restrict__ content, const void* __restrict__ emb,
    const int* __restrict__ flagp,
    const u16* __restrict__ Wp1, const u16* __restrict__ bp1,
    const u16* __restrict__ Wp2, const u16* __restrict__ bp2,
    const u16* __restrict__ Wexp, const u16* __restrict__ bexp,
    u16* __restrict__ hbuf,
    const int* __restrict__ src, const int* __restrict__ dst,
    int* __restrict__ cursor, int* __restrict__ esrc)
{
    __shared__ __align__(16) u16 sA[64 * 64];    //  8 KB  (emb A-tile, swizzled)
    __shared__ __align__(16) u16 sB[384 * 32];   // 24 KB  (B k-plane)
    __shared__ __align__(16) u16 T[64 * 384];    // 48 KB  (content A-tile, then C1)

    const int g13 = blockIdx.x / 13, r13 = blockIdx.x % 13;
    if (r13 >= 8) {                      // ---- fill role (4 edges/thread) ----
        int fb = g13 * 5 + (r13 - 8);
        if (fb >= NB_CNT4) return;
        int base = (fb * 512 + threadIdx.x) * 4;
        if (base < NEDGES) {
            int4 s4 = *(const int4*)(src + base);
            int4 d4 = *(const int4*)(dst + base);
            int p0 = atomicAdd(&cursor[d4.x], 1);
            int p1 = atomicAdd(&cursor[d4.y], 1);
            int p2 = atomicAdd(&cursor[d4.z], 1);
            int p3 = atomicAdd(&cursor[d4.w], 1);
            if ((unsigned)p0 < (unsigned)NEDGES) esrc[p0] = s4.x;
            if ((unsigned)p1 < (unsigned)NEDGES) esrc[p1] = s4.y;
            if ((unsigned)p2 < (unsigned)NEDGES) esrc[p2] = s4.z;
            if ((unsigned)p3 < (unsigned)NEDGES) esrc[p3] = s4.w;
        }
        return;
    }
    // ---- init role ----
    const int iid = g13 * 8 + r13;
    if (iid >= 782) return;
    const int bm = iid * 64;
    const int t = threadIdx.x;
    const int wave = t >> 6, lane = t & 63;
    const int quad = lane >> 4, l16 = lane & 15;
    const int wm = wave >> 2, wn = wave & 3;     // wave tile: 32 rows (x N cols)
    const int lrow = lane >> 2, lcol = (lane & 3) * 8;
    const int fl = *flagp;

    // ---- stage emb A-tile (64x64) -> sA, converted, XOR-swizzled -------------
    {
        int row = t >> 3;                // 0..63
        int c0 = (t & 7) * 8;            // 0..56
        int gm = bm + row;
        u16 o[8];
        if (gm < NNODES) {
            if (fl) {
                const float* ep = (const float*)emb + (size_t)gm * EDIM + c0;
                float4 x = *(const float4*)ep;
                float4 y = *(const float4*)(ep + 4);
                o[0]=f2bf(x.x); o[1]=f2bf(x.y); o[2]=f2bf(x.z); o[3]=f2bf(x.w);
                o[4]=f2bf(y.x); o[5]=f2bf(y.y); o[6]=f2bf(y.z); o[7]=f2bf(y.w);
            } else {
                const u16* ep = (const u16*)emb + (size_t)gm * EDIM + c0;
                ushort4 x = *(const ushort4*)ep;
                ushort4 y = *(const ushort4*)(ep + 4);
                o[0]=x.x; o[1]=x.y; o[2]=x.z; o[3]=x.w;
                o[4]=y.x; o[5]=y.y; o[6]=y.z; o[7]=y.w;
            }
        } else {
            #pragma unroll
            for (int k = 0; k < 8; ++k) o[k] = 0;
        }
        u16* d = &sA[(row * 64 + c0) ^ ((row & 7) << 3)];
        *(ushort4*)d = (ushort4){o[0], o[1], o[2], o[3]};
        *(ushort4*)(d + 4) = (ushort4){o[4], o[5], o[6], o[7]};
    }
    // ---- stage content A-tile (64x384, 300 real cols) -> T, converted --------
    #pragma unroll
    for (int j = 0; j < 6; ++j) {
        int idx = (j * 512 + t) * 8;     // 0..24568
        int row = idx / 384;
        int c0 = idx % 384;              // multiple of 8
        int gm = bm + row;
        u16 o[8];
        if (gm < NNODES && c0 + 8 <= 300) {
            if (fl) {
                const float* cp = (const float*)content + (size_t)gm * 300 + c0;
                float4 x = *(const float4*)cp;
                float4 y = *(const float4*)(cp + 4);
                o[0]=f2bf(x.x); o[1]=f2bf(x.y); o[2]=f2bf(x.z); o[3]=f2bf(x.w);
                o[4]=f2bf(y.x); o[5]=f2bf(y.y); o[6]=f2bf(y.z); o[7]=f2bf(y.w);
            } else {
                const u16* cp = (const u16*)content + (size_t)gm * 300 + c0;
                ushort4 x = *(const ushort4*)cp;       // 8B-aligned (row*600%8==0)
                ushort4 y = *(const ushort4*)(cp + 4);
                o[0]=x.x; o[1]=x.y; o[2]=x.z; o[3]=x.w;
                o[4]=y.x; o[5]=y.y; o[6]=y.z; o[7]=y.w;
            }
        } else if (gm < NNODES && c0 < 300) {          // partial chunk (c0==296)
            #pragma unroll
            for (int k = 0; k < 8; ++k) {
                int c = c0 + k;
                o[k] = (c < 300)
                    ? (fl ? f2bf(((const float*)content)[(size_t)gm * 300 + c])
                          : ((const u16*)content)[(size_t)gm * 300 + c])
                    : (u16)0;
            }
        } else {
            #pragma unroll
            for (int k = 0; k < 8; ++k) o[k] = 0;
        }
        u16* d = &T[(row * 384 + c0) ^ ((row & 7) << 3)];
        *(ushort4*)d = (ushort4){o[0], o[1], o[2], o[3]};
        *(ushort4*)(d + 4) = (ushort4){o[4], o[5], o[6], o[7]};
    }
    __syncthreads();

    // ---------------- phase 1: proj1, K=384, N=384, A = T ---------------------
    floatx4 a1[2][6];
    #pragma unroll
    for (int i = 0; i < 2; ++i)
        #pragma unroll
        for (int j = 0; j < 6; ++j) a1[i][j] = (floatx4){0.f, 0.f, 0.f, 0.f};
    for (int kt = 0; kt < 384; kt += 32) {
        #pragma unroll
        for (int c = 0; c < 3; ++c) {
            int r0 = wave * 48 + c * 16;
            gload16(Wp1 + (size_t)(r0 + lrow) * NCPAD + kt + lcol, &sB[r0 * 32]);
        }
        __syncthreads();
        short8 af[2];
        #pragma unroll
        for (int mt = 0; mt < 2; ++mt) {
            int row = wm * 32 + mt * 16 + l16;
            af[mt] = *(const short8*)&T[(row * 384 + kt + quad * 8) ^ ((row & 7) << 3)];
        }
        #pragma unroll
        for (int nt = 0; nt < 6; ++nt) {
            short8 bf = *(const short8*)&sB[(wn * 96 + nt * 16 + l16) * 32 + quad * 8];
            a1[0][nt] = __builtin_amdgcn_mfma_f32_16x16x32_bf16(af[0], bf, a1[0][nt], 0, 0, 0);
            a1[1][nt] = __builtin_amdgcn_mfma_f32_16x16x32_bf16(af[1], bf, a1[1][nt], 0, 0, 0);
        }
        __syncthreads();
    }
    // epilogue 1: bias + lrelu -> overwrite T (all A reads done at last barrier)
    #pragma unroll
    for (int nt = 0; nt < 6; ++nt) {
        int col = wn * 96 + nt * 16 + l16;
        float bv = bf2f(bp1[col]);
        #pragma unroll
        for (int mt = 0; mt < 2; ++mt)
            #pragma unroll
            for (int rr = 0; rr < 4; ++rr) {
                int row = wm * 32 + mt * 16 + quad * 4 + rr;
                float v = a1[mt][nt][rr] + bv;
                v = v > 0.f ? v : 0.1f * v;
                T[(row * NCPAD + col) ^ ((row & 7) << 3)] = f2bf(v);
            }
    }
    __syncthreads();

    // ---------------- phase 2: proj2, K=384, A = T (LDS), N=256 ---------------
    floatx4 a2[2][4];
    #pragma unroll
    for (int i = 0; i < 2; ++i)
        #pragma unroll
        for (int j = 0; j < 4; ++j) a2[i][j] = (floatx4){0.f, 0.f, 0.f, 0.f};
    for (int kt = 0; kt < 384; kt += 32) {
        #pragma unroll
        for (int c = 0; c < 2; ++c) {
            int r0 = wave * 32 + c * 16;
            gload16(Wp2 + (size_t)(r0 + lrow) * NCPAD + kt + lcol, &sB[r0 * 32]);
        }
        __syncthreads();
        short8 af[2];
        #pragma unroll
        for (int mt = 0; mt < 2; ++mt) {
            int row = wm * 32 + mt * 16 + l16;
            af[mt] = *(const short8*)&T[(row * NCPAD + kt + quad * 8) ^ ((row & 7) << 3)];
        }
        #pragma unroll
        for (int nt = 0; nt < 4; ++nt) {
            short8 bf = *(const short8*)&sB[(wn * 64 + nt * 16 + l16) * 32 + quad * 8];
            a2[0][nt] = __builtin_amdgcn_mfma_f32_16x16x32_bf16(af[0], bf, a2[0][nt], 0, 0, 0);
            a2[1][nt] = __builtin_amdgcn_mfma_f32_16x16x32_bf16(af[1], bf, a2[1][nt], 0, 0, 0);
        }
        __syncthreads();
    }

    // ---------------- phase 3: expansion, K=64, N=256, A = sA -----------------
    floatx4 aE[2][4];
    #pragma unroll
    for (int i = 0; i < 2; ++i)
        #pragma unroll
        for (int j = 0; j < 4; ++j) aE[i][j] = (floatx4){0.f, 0.f, 0.f, 0.f};
    for (int kt = 0; kt < 64; kt += 32) {
        #pragma unroll
        for (int c = 0; c < 2; ++c) {
            int r0 = wave * 32 + c * 16;
            gload16(Wexp + (size_t)(r0 + lrow) * EDIM + kt + lcol, &sB[r0 * 32]);
        }
        __syncthreads();
        short8 af[2];
        #pragma unroll
        for (int mt = 0; mt < 2; ++mt) {
            int row = wm * 32 + mt * 16 + l16;
            af[mt] = *(const short8*)&sA[(row * 64 + kt + quad * 8) ^ ((row & 7) << 3)];
        }
        #pragma unroll
        for (int nt = 0; nt < 4; ++nt) {
            short8 bf = *(const short8*)&sB[(wn * 64 + nt * 16 + l16) * 32 + quad * 8];
            aE[0][nt] = __builtin_amdgcn_mfma_f32_16x16x32_bf16(af[0], bf, aE[0][nt], 0, 0, 0);
            aE[1][nt] = __builtin_amdgcn_mfma_f32_16x16x32_bf16(af[1], bf, aE[1][nt], 0, 0, 0);
        }
        __syncthreads();
    }

    // epilogue: h = lrelu(E + bexp) + lrelu(C2 + bp2) -> hbuf
    #pragma unroll
    for (int nt = 0; nt < 4; ++nt) {
        int col = wn * 64 + nt * 16 + l16;
        float bE = bf2f(bexp[col]), b2 = bf2f(bp2[col]);
        #pragma unroll
        for (int mt = 0; mt < 2; ++mt)
            #pragma unroll
            for (int rr = 0; rr < 4; ++rr) {
                int row = wm * 32 + mt * 16 + quad * 4 + rr;
                int gm = bm + row;
                if (gm < NNODES) {
                    float hE = aE[mt][nt][rr] + bE; hE = hE > 0.f ? hE : 0.1f * hE;
                    float c2 = a2[mt][nt][rr] + b2; c2 = c2 > 0.f ? c2 : 0.1f * c2;
                    hbuf[(size_t)gm * FD + col] = f2bf(hE + c2);
                }
            }
    }
}

// -------- fused non-final layer: per 64-row block (row-local pipeline) --------
//   X = lrelu(concat(h,agg)[rows] @ Wc^T + bc)    K=512, N=256
//   T = X / max(||X||row, 1e-6)   (row-ss computed in f32 from accumulators)
//   Y = lrelu(T @ W1^T + b1)                      K=256 (A direct from LDS)
//   Z = Y @ W2^T + b2  -> out rows                K=256
// out == h aliasing is SAFE: all reads/writes of h are to this block's own rows.
__global__ __launch_bounds__(512, 4) void layer_kernel(
    const u16* __restrict__ h, const u16* __restrict__ agg,
    const u16* __restrict__ Wc, const u16* __restrict__ bc,
    const u16* __restrict__ W1, const u16* __restrict__ b1,
    const u16* __restrict__ W2, const u16* __restrict__ b2,
    u16* __restrict__ out)
{
    __shared__ __align__(16) u16 sA[2][64 * 32];     //  8 KB: A k-tile (2 planes)
    __shared__ __align__(16) u16 sB[2][256 * 32];    // 32 KB: B k-tile (2 planes)
    __shared__ __align__(16) u16 T[64 * 256];        // 32 KB: row tile, swizzled
    __shared__ float ssq[4][64];                     //  1 KB: cross-wave row ss
    // 73.25 KB total -> 2 blocks/CU

    const int t = threadIdx.x;
    const int wave = t >> 6, lane = t & 63;
    const int quad = lane >> 4, l16 = lane & 15;
    const int wm = wave >> 2, wn = wave & 3;         // wave tile: 32 rows x 64 cols
    const int lrow = lane >> 2, lcol = (lane & 3) * 8;
    const int bm = blockIdx.x * 64;

    floatx4 acc[2][4];
    #pragma unroll
    for (int i = 0; i < 2; ++i)
        #pragma unroll
        for (int j = 0; j < 4; ++j) acc[i][j] = (floatx4){0.f, 0.f, 0.f, 0.f};

    // ---------------- phase 1: conv GEMM, K=512 over [h | agg] ----------------
    for (int kt = 0; kt < 512; kt += 64) {
        const u16* Ap = (kt < 256) ? h : agg;
        const int kk = kt & 255;
        {   // A: 64 rows x 64 k = 8 calls, 1 per wave
            int hh = wave & 1, r0 = (wave >> 1) * 16;
            gload16(Ap + (size_t)(bm + r0 + lrow) * 256 + kk + hh * 32 + lcol,
                    &sA[hh][r0 * 32]);
        }
        #pragma unroll
        for (int c = 0; c < 4; ++c) {   // B: 256 rows x 64 k = 32 calls, 4 per wave
            int hh = c >> 1, r0 = wave * 32 + (c & 1) * 16;
            gload16(Wc + (size_t)(r0 + lrow) * 512 + kt + hh * 32 + lcol,
                    &sB[hh][r0 * 32]);
        }
        __syncthreads();
        #pragma unroll
        for (int g = 0; g < 2; ++g) {
            short8 af[2], bf[4];
            #pragma unroll
            for (int mt = 0; mt < 2; ++mt)
                af[mt] = *(const short8*)&sA[g][(wm * 32 + mt * 16 + l16) * 32 + quad * 8];
            #pragma unroll
            for (int nt = 0; nt < 4; ++nt)
                bf[nt] = *(const short8*)&sB[g][(wn * 64 + nt * 16 + l16) * 32 + quad * 8];
            #pragma unroll
            for (int mt = 0; mt < 2; ++mt)
                #pragma unroll
                for (int nt = 0; nt < 4; ++nt)
                    acc[mt][nt] = __builtin_amdgcn_mfma_f32_16x16x32_bf16(af[mt], bf[nt], acc[mt][nt], 0, 0, 0);
        }
        __syncthreads();
    }
    // epilogue 1 (two-pass, register-light): f32 row-ss -> normalized bf16 -> T
    {
        float part[2][4];
        #pragma unroll
        for (int mt = 0; mt < 2; ++mt)
            #pragma unroll
            for (int rr = 0; rr < 4; ++rr) part[mt][rr] = 0.f;
        #pragma unroll
        for (int nt = 0; nt < 4; ++nt) {
            float bv = bf2f(bc[wn * 64 + nt * 16 + l16]);
            #pragma unroll
            for (int mt = 0; mt < 2; ++mt)
                #pragma unroll
                for (int rr = 0; rr < 4; ++rr) {
                    float v = acc[mt][nt][rr] + bv;
                    v = v > 0.f ? v : 0.1f * v;
                    part[mt][rr] += v * v;
                }
        }
        #pragma unroll
        for (int off = 1; off < 16; off <<= 1)
            #pragma unroll
            for (int mt = 0; mt < 2; ++mt)
                #pragma unroll
                for (int rr = 0; rr < 4; ++rr)
                    part[mt][rr] += __shfl_xor(part[mt][rr], off);
        if (l16 == 0)
            #pragma unroll
            for (int mt = 0; mt < 2; ++mt)
                #pragma unroll
                for (int rr = 0; rr < 4; ++rr)
                    ssq[wn][wm * 32 + mt * 16 + quad * 4 + rr] = part[mt][rr];
        __syncthreads();
        #pragma unroll
        for (int mt = 0; mt < 2; ++mt)
            #pragma unroll
            for (int rr = 0; rr < 4; ++rr) {
                int row = wm * 32 + mt * 16 + quad * 4 + rr;
                float s = 1.0f / fmaxf(sqrtf(ssq[0][row] + ssq[1][row] +
                                             ssq[2][row] + ssq[3][row]), 1e-6f);
                #pragma unroll
                for (int nt = 0; nt < 4; ++nt) {
                    int col = wn * 64 + nt * 16 + l16;
                    float v = acc[mt][nt][rr] + bf2f(bc[col]);
                    v = v > 0.f ? v : 0.1f * v;
                    T[(row * 256 + col) ^ ((row & 7) << 3)] = f2bf(v * s);
                }
            }
        __syncthreads();
    }

    // ---------------- phase 2: Wo1 GEMM, K=256, A = T (LDS-resident) ----------
    #pragma unroll
    for (int i = 0; i < 2; ++i)
        #pragma unroll
        for (int j = 0; j < 4; ++j) acc[i][j] = (floatx4){0.f, 0.f, 0.f, 0.f};
    for (int kt = 0; kt < 256; kt += 64) {
        #pragma unroll
        for (int c = 0; c < 4; ++c) {
            int hh = c >> 1, r0 = wave * 32 + (c & 1) * 16;
            gload16(W1 + (size_t)(r0 + lrow) * 256 + kt + hh * 32 + lcol,
                    &sB[hh][r0 * 32]);
        }
        __syncthreads();
        #pragma unroll
        for (int g = 0; g < 2; ++g) {
            short8 af[2], bf[4];
            #pragma unroll
            for (int mt = 0; mt < 2; ++mt) {
                int row = wm * 32 + mt * 16 + l16;
                af[mt] = *(const short8*)&T[(row * 256 + kt + g * 32 + quad * 8) ^ ((row & 7) << 3)];
            }
            #pragma unroll
            for (int nt = 0; nt < 4; ++nt)
                bf[nt] = *(const short8*)&sB[g][(wn * 64 + nt * 16 + l16) * 32 + quad * 8];
            #pragma unroll
            for (int mt = 0; mt < 2; ++mt)
                #pragma unroll
                for (int nt = 0; nt < 4; ++nt)
                    acc[mt][nt] = __builtin_amdgcn_mfma_f32_16x16x32_bf16(af[mt], bf[nt], acc[mt][nt], 0, 0, 0);
        }
        __syncthreads();
    }
    // epilogue 2: bias + lrelu -> T (all reads of T done: last k-iter barrier)
    #pragma unroll
    for (int nt = 0; nt < 4; ++nt) {
        int col = wn * 64 + nt * 16 + l16;
        float bv = bf2f(b1[col]);
        #pragma unroll
        for (int mt = 0; mt < 2; ++mt) {
            #pragma unroll
            for (int r = 0; r < 4; ++r) {
                int row = wm * 32 + mt * 16 + quad * 4 + r;
                float v = acc[mt][nt][r] + bv;
                v = v > 0.f ? v : 0.1f * v;
                T[(row * 256 + col) ^ ((row & 7) << 3)] = f2bf(v);
            }
        }
    }
    __syncthreads();

    // ---------------- phase 3: Wo2 GEMM, K=256, A = T -> global ---------------
    #pragma unroll
    for (int i = 0; i < 2; ++i)
        #pragma unroll
        for (int j = 0; j < 4; ++j) acc[i][j] = (floatx4){0.f, 0.f, 0.f, 0.f};
    for (int kt = 0; kt < 256; kt += 64) {
        #pragma unroll
        for (int c = 0; c < 4; ++c) {
            int hh = c >> 1, r0 = wave * 32 + (c & 1) * 16;
            gload16(W2 + (size_t)(r0 + lrow) * 256 + kt + hh * 32 + lcol,
                    &sB[hh][r0 * 32]);
        }
        __syncthreads();
        #pragma unroll
        for (int g = 0; g < 2; ++g) {
            short8 af[2], bf[4];
            #pragma unroll
            for (int mt = 0; mt < 2; ++mt) {
                int row = wm * 32 + mt * 16 + l16;
                af[mt] = *(const short8*)&T[(row * 256 + kt + g * 32 + quad * 8) ^ ((row & 7) << 3)];
            }
            #pragma unroll
            for (int nt = 0; nt < 4; ++nt)
                bf[nt] = *(const short8*)&sB[g][(wn * 64 + nt * 16 + l16) * 32 + quad * 8];
            #pragma unroll
            for (int mt = 0; mt < 2; ++mt)
                #pragma unroll
                for (int nt = 0; nt < 4; ++nt)
                    acc[mt][nt] = __builtin_amdgcn_mfma_f32_16x16x32_bf16(af[mt], bf[nt], acc[mt][nt], 0, 0, 0);
        }
        __syncthreads();
    }
    // epilogue 3: bias (no act) -> out (bf16), guard real rows
    #pragma unroll
    for (int nt = 0; nt < 4; ++nt) {
        int col = wn * 64 + nt * 16 + l16;
        float bv = bf2f(b2[col]);
        #pragma unroll
        for (int mt = 0; mt < 2; ++mt) {
            #pragma unroll
            for (int r = 0; r < 4; ++r) {
                int row = wm * 32 + mt * 16 + quad * 4 + r;
                int gm = bm + row;
                if (gm < NNODES) {
                    float v = acc[mt][nt][r] + bv;
                    out[(size_t)gm * 256 + col] = f2bf(v);
                }
            }
        }
    }
}

// -------- fused final layer: conv (K=512) + f32 row L2-norm -> d_out f32 ------
__global__ __launch_bounds__(512, 4) void final_kernel(
    const u16* __restrict__ h, const u16* __restrict__ agg,
    const u16* __restrict__ Wc, const u16* __restrict__ bc,
    float* __restrict__ out)
{
    __shared__ __align__(16) u16 sA[2][64 * 32];     //  8 KB
    __shared__ __align__(16) u16 sB[2][256 * 32];    // 32 KB
    __shared__ float ssq[4][64];                     //  1 KB

    const int t = threadIdx.x;
    const int wave = t >> 6, lane = t & 63;
    const int quad = lane >> 4, l16 = lane & 15;
    const int wm = wave >> 2, wn = wave & 3;
    const int lrow = lane >> 2, lcol = (lane & 3) * 8;
    const int bm = blockIdx.x * 64;

    floatx4 acc[2][4];
    #pragma unroll
    for (int i = 0; i < 2; ++i)
        #pragma unroll
        for (int j = 0; j < 4; ++j) acc[i][j] = (floatx4){0.f, 0.f, 0.f, 0.f};

    for (int kt = 0; kt < 512; kt += 64) {
        const u16* Ap = (kt < 256) ? h : agg;
        const int kk = kt & 255;
        {
            int hh = wave & 1, r0 = (wave >> 1) * 16;
            gload16(Ap + (size_t)(bm + r0 + lrow) * 256 + kk + hh * 32 + lcol,
                    &sA[hh][r0 * 32]);
        }
        #pragma unroll
        for (int c = 0; c < 4; ++c) {
            int hh = c >> 1, r0 = wave * 32 + (c & 1) * 16;
            gload16(Wc + (size_t)(r0 + lrow) * 512 + kt + hh * 32 + lcol,
                    &sB[hh][r0 * 32]);
        }
        __syncthreads();
        #pragma unroll
        for (int g = 0; g < 2; ++g) {
            short8 af[2], bf[4];
            #pragma unroll
            for (int mt = 0; mt < 2; ++mt)
                af[mt] = *(const short8*)&sA[g][(wm * 32 + mt * 16 + l16) * 32 + quad * 8];
            #pragma unroll
            for (int nt = 0; nt < 4; ++nt)
                bf[nt] = *(const short8*)&sB[g][(wn * 64 + nt * 16 + l16) * 32 + quad * 8];
            #pragma unroll
            for (int mt = 0; mt < 2; ++mt)
                #pragma unroll
                for (int nt = 0; nt < 4; ++nt)
                    acc[mt][nt] = __builtin_amdgcn_mfma_f32_16x16x32_bf16(af[mt], bf[nt], acc[mt][nt], 0, 0, 0);
        }
        __syncthreads();
    }
    // epilogue: bias (no act), f32 row-ss, normalized f32 store
    float part[2][4];
    #pragma unroll
    for (int mt = 0; mt < 2; ++mt)
        #pragma unroll
        for (int rr = 0; rr < 4; ++rr) part[mt][rr] = 0.f;
    #pragma unroll
    for (int nt = 0; nt < 4; ++nt) {
        float bv = bf2f(bc[wn * 64 + nt * 16 + l16]);
        #pragma unroll
        for (int mt = 0; mt < 2; ++mt)
            #pragma unroll
            for (int rr = 0; rr < 4; ++rr) {
                float v = acc[mt][nt][rr] + bv;
                part[mt][rr] += v * v;
            }
    }
    #pragma unroll
    for (int off = 1; off < 16; off <<= 1)
        #pragma unroll
        for (int mt = 0; mt < 2; ++mt)
            #pragma unroll
            for (int rr = 0; rr < 4; ++rr)
                part[mt][rr] += __shfl_xor(part[mt][rr], off);
    if (l16 == 0)
        #pragma unroll
        for (int mt = 0; mt < 2; ++mt)
            #pragma unroll
            for (int rr = 0; rr < 4; ++rr)
                ssq[wn][wm * 32 + mt * 16 + quad * 4 + rr] = part[mt][rr];
    __syncthreads();
    #pragma unroll
    for (int mt = 0; mt < 2; ++mt)
        #pragma unroll
        for (int rr = 0; rr < 4; ++rr) {
            int row = wm * 32 + mt * 16 + quad * 4 + rr;
            int gm = bm + row;
            float s = 1.0f / fmaxf(sqrtf(ssq[0][row] + ssq[1][row] +
                                         ssq[2][row] + ssq[3][row]), 1e-6f);
            if (gm < NNODES) {
                #pragma unroll
                for (int nt = 0; nt < 4; ++nt) {
                    int col = wn * 64 + nt * 16 + l16;
                    out[(size_t)gm * 256 + col] = (acc[mt][nt][rr] + bf2f(bc[col])) * s;
                }
            }
        }
}

// ------------- neighbor-mean aggregation (pull, CSR, 8 rows in flight) --------
// wid forced to SGPR via readfirstlane -> rs/esrc loads go scalar, freeing the
// vector-memory queue for the 512B row gathers; 8-deep ILP in the main loop.
__global__ __launch_bounds__(256) void agg_kernel(
    const u16* h, const int* row_start, const int* esrc,
    const float* inv_w, u16* out)
{
    int gid = blockIdx.x * blockDim.x + threadIdx.x;
    int wid = __builtin_amdgcn_readfirstlane(gid >> 6);   // wave-uniform
    int lane = threadIdx.x & 63;
    if (wid >= NNODES) return;
    int e0 = row_start[wid], e1 = row_start[wid + 1];
    e0 = max(0, min(e0, NEDGES));
    e1 = max(e0, min(e1, NEDGES));
    float a0 = 0.f, a1 = 0.f, a2 = 0.f, a3 = 0.f;
    int e = e0;
    for (; e + 8 <= e1; e += 8) {
        int u[8];
        #pragma unroll
        for (int k = 0; k < 8; ++k) {
            u[k] = esrc[e + k];
            if ((unsigned)u[k] >= (unsigned)NNODES) u[k] = 0;
        }
        ushort4 tv[8];
        #pragma unroll
        for (int k = 0; k < 8; ++k)
            tv[k] = *(const ushort4*)(h + (size_t)u[k] * FD + lane * 4);
        #pragma unroll
        for (int k = 0; k < 8; ++k) {
            a0 += bf2f(tv[k].x); a1 += bf2f(tv[k].y);
            a2 += bf2f(tv[k].z); a3 += bf2f(tv[k].w);
        }
    }
    for (; e + 2 <= e1; e += 2) {
        int u0 = esrc[e + 0]; if ((unsigned)u0 >= (unsigned)NNODES) u0 = 0;
        int u1 = esrc[e + 1]; if ((unsigned)u1 >= (unsigned)NNODES) u1 = 0;
        ushort4 t0 = *(const ushort4*)(h + (size_t)u0 * FD + lane * 4);
        ushort4 t1 = *(const ushort4*)(h + (size_t)u1 * FD + lane * 4);
        a0 += bf2f(t0.x) + bf2f(t1.x);
        a1 += bf2f(t0.y) + bf2f(t1.y);
        a2 += bf2f(t0.z) + bf2f(t1.z);
        a3 += bf2f(t0.w) + bf2f(t1.w);
    }
    for (; e < e1; ++e) {
        int u = esrc[e];
        if ((unsigned)u >= (unsigned)NNODES) u = 0;
        ushort4 tv = *(const ushort4*)(h + (size_t)u * FD + lane * 4);
        a0 += bf2f(tv.x); a1 += bf2f(tv.y); a2 += bf2f(tv.z); a3 += bf2f(tv.w);
    }
    float s = inv_w[wid];
    ushort4 ov;
    ov.x = f2bf(a0 * s); ov.y = f2bf(a1 * s); ov.z = f2bf(a2 * s); ov.w = f2bf(a3 * s);
    *(ushort4*)(out + (size_t)wid * FD + lane * 4) = ov;
}

extern "C" void kernel_launch(void* const* d_in, const int* in_sizes, int n_in,
                              void* d_out, int out_size, void* d_ws, size_t ws_size,
                              hipStream_t stream) {
    const void* content = d_in[1];
    const int* src      = (const int*)d_in[2];
    const int* dst      = (const int*)d_in[3];
    const void* emb     = d_in[4];

    // ---- workspace layout (all offsets 256B-aligned) -------------------------
    char* ws = (char*)d_ws;
    u16* arena = (u16*)(ws);                        // padded weights bf16
    u16* hbuf  = (u16*)(ws + 1840640);              // [50048 x 256] bf16
    u16* buf2  = (u16*)(ws + 27465216);             // [50048 x 256] (h_agg)
    int*   deg    = (int*)(ws + 78714368);
    int*   rs     = (int*)(ws + 78914560);
    int*   cursor = (int*)(ws + 79114752);
    float* inv_w  = (float*)(ws + 79314944);
    int*   esrc   = (int*)(ws + 79515136);          // 4 MB
    int*   bsum   = (int*)(ws + 83515648);
    int*   flag   = (int*)(ws + 83516672);

    u16* aWexp  = arena;            u16* aBexp  = arena + 16384;
    u16* aWp1   = arena + 16640;    u16* aBp1   = arena + 164096;
    u16* aWp2   = arena + 164480;   u16* aBp2   = arena + 262784;
    u16* aWconv = arena + 263040;   u16* aBconv = arena + 656256;
    u16* aWo1   = arena + 657024;   u16* aBo1   = arena + 788096;
    u16* aWo2   = arena + 788608;   u16* aBo2   = arena + 919680;

    const int MB64 = NROWS_PAD / 64;   // 782

    // ---- dtype probe, then prep (weight convert + vectorized count) ----------
    detect_kernel<<<1, 256, 0, stream>>>((const u16*)content, flag);
    hipMemsetAsync(deg, 0, (size_t)NNODES * 4, stream);
    prep_kernel<<<PREP_GRID, 512, 0, stream>>>(arena, flag,
        d_in[5], d_in[6], d_in[7], d_in[8], d_in[9], d_in[10], d_in[11],
        d_in[12], d_in[13], d_in[14], d_in[15], d_in[16], dst, deg);

    // ---- CSR scans (tiny) ----
    scan1_kernel<<<NSCAN, 256, 0, stream>>>(deg, bsum);
    scan2_kernel<<<1, 256, 0, stream>>>(bsum, rs);
    scan3_kernel<<<NSCAN, 256, 0, stream>>>(deg, bsum, rs, cursor, inv_w);

    // ---- union: fused init (MFMA-heavy, direct src staging) + CSR fill -------
    initfill_kernel<<<IF_GRID, 512, 0, stream>>>(content, emb, flag,
        aWp1, aBp1, aWp2, aBp2, aWexp, aBexp, hbuf, src, dst, cursor, esrc);

    // ---- layers (separate agg: latency-bound gather keeps full occupancy) ----
    for (int i = 0; i < 3; ++i) {
        agg_kernel<<<(NNODES * 64) / 256, 256, 0, stream>>>(hbuf, rs, esrc, inv_w, buf2);
        if (i < 2) {
            layer_kernel<<<dim3(MB64), dim3(512), 0, stream>>>(
                hbuf, buf2,
                aWconv + (size_t)i * FD * 2 * FD, aBconv + (size_t)i * FD,
                aWo1 + (size_t)i * FD * FD, aBo1 + (size_t)i * FD,
                aWo2 + (size_t)i * FD * FD, aBo2 + (size_t)i * FD,
                hbuf);
        } else {
            final_kernel<<<dim3(MB64), dim3(512), 0, stream>>>(
                hbuf, buf2,
                aWconv + (size_t)i * FD * 2 * FD, aBconv + (size_t)i * FD,
                (float*)d_out);
        }
    }
}